// Round 18
// baseline (23.757 us; speedup 1.0000x reference)
//
#include <hip/hip_runtime.h>

// out[n,k] = sum_{i,j} x[n,i] * W[k,i,j] * x[n,j]   (N=262144 rows, D=32)
// R18 vs R17 (22.8us): BLOCK FLOW. R17's grid (512 x 1024thr = exactly 2
// blocks/CU) is one-shot lockstep: every CU load-bursts, computes, drains --
// no block-level overlap. Fills hit 6.9 TB/s precisely because 1000s of small
// blocks flow. Now: 1024 blocks x 512 thr (256 rows/block, 1 tile/wave),
// LDS = btab 33K + stage 18K = 51K -> 3 blocks/CU (24 waves/CU; R14==R15
// showed 24 vs 32 waves is flat), grid 1024 > 768 resident -> staggered
// start/finish, stores of finishing blocks overlap loads of starting ones.
// Micro: XS 20->18 (stage read conflicts 4-way -> 2-way, free), btab copy
// in two phases (prologue reg pressure < 64). K-loop/math identical
// (absmax 0.25).
//
// Algorithm: symmetrized circular-diagonal GEMM. p = d*32+i, d=0..16,
// z[n,p] = x[n,i]*x[n,(i+d)&31], Wf[p,k] = W[k,i,j]+W[k,j,i] (d=0 diag,
// d=16 half), K = 528 = 33 MFMA steps of v_mfma_f32_32x32x16_f16.

typedef _Float16 f16x2 __attribute__((ext_vector_type(2)));
typedef _Float16 f16x4 __attribute__((ext_vector_type(4)));
typedef _Float16 f16x8 __attribute__((ext_vector_type(8)));
typedef float    f32x16 __attribute__((ext_vector_type(16)));

static __device__ __forceinline__ unsigned int pk2_f16(float lo, float hi) {
    return __builtin_bit_cast(unsigned int, __builtin_amdgcn_cvt_pkrtz(lo, hi));
}
static __device__ __forceinline__ f16x2 u2h(unsigned int u) {
    return __builtin_bit_cast(f16x2, u);
}
static __device__ __forceinline__ unsigned short f16b(float f) {
    _Float16 h = (_Float16)f;
    return __builtin_bit_cast(unsigned short, h);
}

// ---- prep (R16): one block per k; stage W_k in LDS coalesced, gather ----
__global__ __launch_bounds__(256)
void prep_btab_sym(const float* __restrict__ W, unsigned short* __restrict__ bt) {
    __shared__ float Wlds[1024];                    // 4 KiB = W[k,:,:]
    const int k = blockIdx.x;                       // 0..31
    const int t = threadIdx.x;
    {
        const float4* src = (const float4*)(W + k * 1024);
        ((float4*)Wlds)[t] = src[t];
    }
    __syncthreads();
    if (t < 66) {                                   // 33 n x 2 l-halves
        int n  = t >> 1;
        int lh = t & 1;                             // l = k + lh*32
        int d  = (n == 32) ? 16 : (n >> 1);
        int q  = (n == 32) ? 0  : (n & 1);
        unsigned short v[8];
        #pragma unroll
        for (int b = 0; b < 8; ++b) {
            int i = q * 16 + lh * 8 + b;
            int j = (i + d) & 31;
            float s = (d == 0) ? Wlds[i * 32 + i]
                               : Wlds[i * 32 + j] + Wlds[j * 32 + i];
            v[b] = f16b(s);
        }
        uint4 pk;
        pk.x = (unsigned int)v[0] | ((unsigned int)v[1] << 16);
        pk.y = (unsigned int)v[2] | ((unsigned int)v[3] << 16);
        pk.z = (unsigned int)v[4] | ((unsigned int)v[5] << 16);
        pk.w = (unsigned int)v[6] | ((unsigned int)v[7] << 16);
        ((uint4*)bt)[n * 64 + k + lh * 32] = pk;
    }
}

#define XS 18   // u32 per staged row: gcd(18,32)=2 -> 2-way read aliasing (free)

__global__ __launch_bounds__(512, 8)
void quadform_kernel(const float* __restrict__ x,
                     const unsigned short* __restrict__ bt_ws,
                     float* __restrict__ out) {
    __shared__ __align__(16) unsigned short btab[33 * 64 * 8];   // 33792 B
    __shared__ __align__(16) unsigned int   xstage[256 * XS];    // 18432 B

    const int tid  = threadIdx.x;
    const int lane = tid & 63;
    const int wave = tid >> 6;
    const int hi   = lane >> 5;
    const int rl   = lane & 31;
    const long blockrow = (long)blockIdx.x * 256;
    const long wrow = blockrow + wave * 32;         // this wave's 32 rows

    // ---- 1) issue coalesced x loads (HBM, slow - first) ----
    const float4* xsrc = (const float4*)(x + blockrow * 32);
    float4 xg0 = xsrc[tid];
    float4 xg1 = xsrc[512 + tid];
    float4 xg2 = xsrc[1024 + tid];
    float4 xg3 = xsrc[1536 + tid];

    // ---- 2) btab copy phase 1 (L2-resident source) ----
    const uint4* bsrc = (const uint4*)bt_ws;
    uint4* bdst = (uint4*)btab;
    {
        uint4 b0 = bsrc[tid];
        uint4 b1 = bsrc[512 + tid];
        bdst[tid]       = b0;
        bdst[512 + tid] = b1;
    }

    // ---- 3) pack + stage x (waits on x loads; hides under copy) ----
    #pragma unroll
    for (int c = 0; c < 4; ++c) {
        float4 v = (c == 0) ? xg0 : (c == 1) ? xg1 : (c == 2) ? xg2 : xg3;
        int idx = c * 512 + tid;                    // float4 index 0..2047
        int row = idx >> 3;                         // 8 float4 per row
        int sub = idx & 7;
        uint2 w2;
        w2.x = pk2_f16(v.x, v.y);
        w2.y = pk2_f16(v.z, v.w);
        *(uint2*)&xstage[row * XS + sub * 2] = w2;
    }

    // ---- 4) btab copy phase 2 ----
    {
        uint4 b2 = bsrc[1024 + tid];
        uint4 b3 = bsrc[1536 + tid];
        bdst[1024 + tid] = b2;
        bdst[1536 + tid] = b3;
        if (tid < 64) bdst[2048 + tid] = bsrc[2048 + tid];
    }
    __syncthreads();

    // ---- read own row from stage, pre-rotate by hi*4 (static indices) ----
    unsigned int ypk[16];
    {
        unsigned int xpk[16];
        const unsigned int* xr = &xstage[(wave * 32 + rl) * XS];
        #pragma unroll
        for (int c = 0; c < 4; ++c) {
            uint4 v = *(const uint4*)(xr + c * 4);
            xpk[c * 4 + 0] = v.x;
            xpk[c * 4 + 1] = v.y;
            xpk[c * 4 + 2] = v.z;
            xpk[c * 4 + 3] = v.w;
        }
        #pragma unroll
        for (int c = 0; c < 16; ++c)
            ypk[c] = hi ? xpk[(c + 4) & 15] : xpk[c];
    }

    f32x16 acc;
    #pragma unroll
    for (int e = 0; e < 16; ++e) acc[e] = 0.0f;

    // ---- K loop: 33 steps (17 circular diagonals), fully unrolled, SSA ----
    #pragma unroll
    for (int s = 0; s < 33; ++s) {
        const int d   = (s == 32) ? 16 : (s >> 1);
        const int q8  = ((s == 32) ? 0 : (s & 1)) * 8;
        const int dh  = d >> 1;
        const bool od = (d & 1) != 0;
        f16x8 bfrag = *(const f16x8*)(&btab[(s * 64 + lane) * 8]);

        f16x2 b0 = od ? u2h(__builtin_amdgcn_perm(ypk[(q8 + 0 + dh + 1) & 15], ypk[(q8 + 0 + dh) & 15], 0x05040302u)) : u2h(ypk[(q8 + 0 + dh) & 15]);
        f16x2 b1 = od ? u2h(__builtin_amdgcn_perm(ypk[(q8 + 1 + dh + 1) & 15], ypk[(q8 + 1 + dh) & 15], 0x05040302u)) : u2h(ypk[(q8 + 1 + dh) & 15]);
        f16x2 b2 = od ? u2h(__builtin_amdgcn_perm(ypk[(q8 + 2 + dh + 1) & 15], ypk[(q8 + 2 + dh) & 15], 0x05040302u)) : u2h(ypk[(q8 + 2 + dh) & 15]);
        f16x2 b3 = od ? u2h(__builtin_amdgcn_perm(ypk[(q8 + 3 + dh + 1) & 15], ypk[(q8 + 3 + dh) & 15], 0x05040302u)) : u2h(ypk[(q8 + 3 + dh) & 15]);
        f16x2 a0 = u2h(ypk[q8 + 0]) * b0;
        f16x2 a1 = u2h(ypk[q8 + 1]) * b1;
        f16x2 a2 = u2h(ypk[q8 + 2]) * b2;
        f16x2 a3 = u2h(ypk[q8 + 3]) * b3;
        f16x4 lo = __builtin_shufflevector(a0, a1, 0, 1, 2, 3);
        f16x4 hf = __builtin_shufflevector(a2, a3, 0, 1, 2, 3);
        f16x8 a  = __builtin_shufflevector(lo, hf, 0, 1, 2, 3, 4, 5, 6, 7);
        acc = __builtin_amdgcn_mfma_f32_32x32x16_f16(a, bfrag, acc, 0, 0, 0);
    }

    // ---- store: one base, 16 constant-offset nontemporal stores ----
    float* ob = out + (wrow + 4 * hi) * 32 + rl;
    #pragma unroll
    for (int e = 0; e < 16; ++e)
        __builtin_nontemporal_store(acc[e], ob + (e & 3) * 32 + (e >> 2) * 256);
}

extern "C" void kernel_launch(void* const* d_in, const int* in_sizes, int n_in,
                              void* d_out, int out_size, void* d_ws, size_t ws_size,
                              hipStream_t stream) {
    const float* x = (const float*)d_in[0];
    const float* W = (const float*)d_in[1];
    float* out = (float*)d_out;
    unsigned short* bt = (unsigned short*)d_ws;    // 33 KiB table

    prep_btab_sym<<<32, 256, 0, stream>>>(W, bt);
    int nrows = in_sizes[0] / 32;          // 262144
    int grid  = nrows / 256;               // 1024 blocks x 512 thr
    quadform_kernel<<<grid, 512, 0, stream>>>(x, bt, out);
}

// Round 19
// 22.813 us; speedup vs baseline: 1.0413x; 1.0413x over previous
//
#include <hip/hip_runtime.h>

// out[n,k] = sum_{i,j} x[n,i] * W[k,i,j] * x[n,j]   (N=262144 rows, D=32)
// R19 vs R17 (22.8us best; R18's 3-block stagger regressed to 23.8): B-REUSE.
// bfrag depends only on (step, lane) -- a wave with 2 row-tiles reads B once
// per step and feeds 2 MFMAs, halving the dominant on-CU pipe term (33
// ds_read_b128/wave: 5.3us/CU at 32 waves -> 2.6us at 16). Cost: state ~112
// regs (ypk 32 + acc 32 AGPR) -> launch_bounds(512,4), 16 waves/CU.
// (L2-direct bfrag checked: 8192 waves x 33KB = 270MB L2 = 8-13us; worse.)
// Geometry: 512 blocks x 512 thr, 8 waves x 64 rows = 512 rows/block;
// LDS = btab 33K + xstage 36K = 69K -> 2 blocks/CU. btab-copy count stays
// at R17's 512. Coalesced x + folded nt-stores + prep v2 retained.
// K-loop math identical (absmax 0.25).
//
// Algorithm: symmetrized circular-diagonal GEMM. p = d*32+i, d=0..16,
// z[n,p] = x[n,i]*x[n,(i+d)&31], Wf[p,k] = W[k,i,j]+W[k,j,i] (d=0 diag,
// d=16 half), K = 528 = 33 MFMA steps of v_mfma_f32_32x32x16_f16.

typedef _Float16 f16x2 __attribute__((ext_vector_type(2)));
typedef _Float16 f16x4 __attribute__((ext_vector_type(4)));
typedef _Float16 f16x8 __attribute__((ext_vector_type(8)));
typedef float    f32x16 __attribute__((ext_vector_type(16)));

static __device__ __forceinline__ unsigned int pk2_f16(float lo, float hi) {
    return __builtin_bit_cast(unsigned int, __builtin_amdgcn_cvt_pkrtz(lo, hi));
}
static __device__ __forceinline__ f16x2 u2h(unsigned int u) {
    return __builtin_bit_cast(f16x2, u);
}
static __device__ __forceinline__ unsigned short f16b(float f) {
    _Float16 h = (_Float16)f;
    return __builtin_bit_cast(unsigned short, h);
}

// ---- prep (R16): one block per k; stage W_k in LDS coalesced, gather ----
__global__ __launch_bounds__(256)
void prep_btab_sym(const float* __restrict__ W, unsigned short* __restrict__ bt) {
    __shared__ float Wlds[1024];                    // 4 KiB = W[k,:,:]
    const int k = blockIdx.x;                       // 0..31
    const int t = threadIdx.x;
    {
        const float4* src = (const float4*)(W + k * 1024);
        ((float4*)Wlds)[t] = src[t];
    }
    __syncthreads();
    if (t < 66) {                                   // 33 n x 2 l-halves
        int n  = t >> 1;
        int lh = t & 1;                             // l = k + lh*32
        int d  = (n == 32) ? 16 : (n >> 1);
        int q  = (n == 32) ? 0  : (n & 1);
        unsigned short v[8];
        #pragma unroll
        for (int b = 0; b < 8; ++b) {
            int i = q * 16 + lh * 8 + b;
            int j = (i + d) & 31;
            float s = (d == 0) ? Wlds[i * 32 + i]
                               : Wlds[i * 32 + j] + Wlds[j * 32 + i];
            v[b] = f16b(s);
        }
        uint4 pk;
        pk.x = (unsigned int)v[0] | ((unsigned int)v[1] << 16);
        pk.y = (unsigned int)v[2] | ((unsigned int)v[3] << 16);
        pk.z = (unsigned int)v[4] | ((unsigned int)v[5] << 16);
        pk.w = (unsigned int)v[6] | ((unsigned int)v[7] << 16);
        ((uint4*)bt)[n * 64 + k + lh * 32] = pk;
    }
}

#define XS 18   // u32 per staged row: gcd(18,32)=2 -> 2-way read aliasing (free)

__global__ __launch_bounds__(512, 4)
void quadform_kernel(const float* __restrict__ x,
                     const unsigned short* __restrict__ bt_ws,
                     float* __restrict__ out) {
    __shared__ __align__(16) unsigned short btab[33 * 64 * 8];   // 33792 B
    __shared__ __align__(16) unsigned int   xstage[512 * XS];    // 36864 B

    const int tid  = threadIdx.x;
    const int lane = tid & 63;
    const int wave = tid >> 6;
    const int hi   = lane >> 5;
    const int rl   = lane & 31;
    const long blockrow = (long)blockIdx.x * 512;
    const long wrow = blockrow + wave * 64;         // 2 tiles: rows wrow..wrow+63

    // ---- 1) issue coalesced x loads (HBM, slow - first): 8 float4/thread ----
    const float4* xsrc = (const float4*)(x + blockrow * 32);
    float4 xg0 = xsrc[tid];
    float4 xg1 = xsrc[512 + tid];
    float4 xg2 = xsrc[1024 + tid];
    float4 xg3 = xsrc[1536 + tid];
    float4 xg4 = xsrc[2048 + tid];
    float4 xg5 = xsrc[2560 + tid];
    float4 xg6 = xsrc[3072 + tid];
    float4 xg7 = xsrc[3584 + tid];

    // ---- 2) btab copy (L2-resident source), 4 uint4/thread + tail ----
    const uint4* bsrc = (const uint4*)bt_ws;
    uint4* bdst = (uint4*)btab;
    {
        uint4 b0 = bsrc[tid];
        uint4 b1 = bsrc[512 + tid];
        uint4 b2 = bsrc[1024 + tid];
        uint4 b3 = bsrc[1536 + tid];
        bdst[tid]        = b0;
        bdst[512 + tid]  = b1;
        bdst[1024 + tid] = b2;
        bdst[1536 + tid] = b3;
        if (tid < 64) bdst[2048 + tid] = bsrc[2048 + tid];
    }

    // ---- 3) pack + stage x (waits on x loads; hides under copy) ----
    #pragma unroll
    for (int c = 0; c < 8; ++c) {
        float4 v = (c == 0) ? xg0 : (c == 1) ? xg1 : (c == 2) ? xg2 :
                   (c == 3) ? xg3 : (c == 4) ? xg4 : (c == 5) ? xg5 :
                   (c == 6) ? xg6 : xg7;
        int idx = c * 512 + tid;                    // float4 index 0..4095
        int row = idx >> 3;                         // 8 float4 per row
        int sub = idx & 7;
        uint2 w2;
        w2.x = pk2_f16(v.x, v.y);
        w2.y = pk2_f16(v.z, v.w);
        *(uint2*)&xstage[row * XS + sub * 2] = w2;
    }
    __syncthreads();

    // ---- read own 2 rows from stage, pre-rotate by hi*4 (static indices) ----
    unsigned int ypk0[16], ypk1[16];
    {
        unsigned int xpk0[16], xpk1[16];
        const unsigned int* xr0 = &xstage[(wave * 64 + rl) * XS];
        const unsigned int* xr1 = &xstage[(wave * 64 + 32 + rl) * XS];
        #pragma unroll
        for (int c = 0; c < 4; ++c) {
            uint4 v0 = *(const uint4*)(xr0 + c * 4);
            uint4 v1 = *(const uint4*)(xr1 + c * 4);
            xpk0[c * 4 + 0] = v0.x; xpk0[c * 4 + 1] = v0.y;
            xpk0[c * 4 + 2] = v0.z; xpk0[c * 4 + 3] = v0.w;
            xpk1[c * 4 + 0] = v1.x; xpk1[c * 4 + 1] = v1.y;
            xpk1[c * 4 + 2] = v1.z; xpk1[c * 4 + 3] = v1.w;
        }
        #pragma unroll
        for (int c = 0; c < 16; ++c) {
            ypk0[c] = hi ? xpk0[(c + 4) & 15] : xpk0[c];
            ypk1[c] = hi ? xpk1[(c + 4) & 15] : xpk1[c];
        }
    }

    f32x16 accA, accB;
    #pragma unroll
    for (int e = 0; e < 16; ++e) { accA[e] = 0.0f; accB[e] = 0.0f; }

    // ---- K loop: 33 steps; ONE bfrag read feeds BOTH tiles' MFMAs ----
    #pragma unroll
    for (int s = 0; s < 33; ++s) {
        const int d   = (s == 32) ? 16 : (s >> 1);
        const int q8  = ((s == 32) ? 0 : (s & 1)) * 8;
        const int dh  = d >> 1;
        const bool od = (d & 1) != 0;
        f16x8 bfrag = *(const f16x8*)(&btab[(s * 64 + lane) * 8]);

        {   // tile 0
            f16x2 b0 = od ? u2h(__builtin_amdgcn_perm(ypk0[(q8 + 0 + dh + 1) & 15], ypk0[(q8 + 0 + dh) & 15], 0x05040302u)) : u2h(ypk0[(q8 + 0 + dh) & 15]);
            f16x2 b1 = od ? u2h(__builtin_amdgcn_perm(ypk0[(q8 + 1 + dh + 1) & 15], ypk0[(q8 + 1 + dh) & 15], 0x05040302u)) : u2h(ypk0[(q8 + 1 + dh) & 15]);
            f16x2 b2 = od ? u2h(__builtin_amdgcn_perm(ypk0[(q8 + 2 + dh + 1) & 15], ypk0[(q8 + 2 + dh) & 15], 0x05040302u)) : u2h(ypk0[(q8 + 2 + dh) & 15]);
            f16x2 b3 = od ? u2h(__builtin_amdgcn_perm(ypk0[(q8 + 3 + dh + 1) & 15], ypk0[(q8 + 3 + dh) & 15], 0x05040302u)) : u2h(ypk0[(q8 + 3 + dh) & 15]);
            f16x2 a0 = u2h(ypk0[q8 + 0]) * b0;
            f16x2 a1 = u2h(ypk0[q8 + 1]) * b1;
            f16x2 a2 = u2h(ypk0[q8 + 2]) * b2;
            f16x2 a3 = u2h(ypk0[q8 + 3]) * b3;
            f16x4 lo = __builtin_shufflevector(a0, a1, 0, 1, 2, 3);
            f16x4 hf = __builtin_shufflevector(a2, a3, 0, 1, 2, 3);
            f16x8 a  = __builtin_shufflevector(lo, hf, 0, 1, 2, 3, 4, 5, 6, 7);
            accA = __builtin_amdgcn_mfma_f32_32x32x16_f16(a, bfrag, accA, 0, 0, 0);
        }
        {   // tile 1 (same bfrag)
            f16x2 b0 = od ? u2h(__builtin_amdgcn_perm(ypk1[(q8 + 0 + dh + 1) & 15], ypk1[(q8 + 0 + dh) & 15], 0x05040302u)) : u2h(ypk1[(q8 + 0 + dh) & 15]);
            f16x2 b1 = od ? u2h(__builtin_amdgcn_perm(ypk1[(q8 + 1 + dh + 1) & 15], ypk1[(q8 + 1 + dh) & 15], 0x05040302u)) : u2h(ypk1[(q8 + 1 + dh) & 15]);
            f16x2 b2 = od ? u2h(__builtin_amdgcn_perm(ypk1[(q8 + 2 + dh + 1) & 15], ypk1[(q8 + 2 + dh) & 15], 0x05040302u)) : u2h(ypk1[(q8 + 2 + dh) & 15]);
            f16x2 b3 = od ? u2h(__builtin_amdgcn_perm(ypk1[(q8 + 3 + dh + 1) & 15], ypk1[(q8 + 3 + dh) & 15], 0x05040302u)) : u2h(ypk1[(q8 + 3 + dh) & 15]);
            f16x2 a0 = u2h(ypk1[q8 + 0]) * b0;
            f16x2 a1 = u2h(ypk1[q8 + 1]) * b1;
            f16x2 a2 = u2h(ypk1[q8 + 2]) * b2;
            f16x2 a3 = u2h(ypk1[q8 + 3]) * b3;
            f16x4 lo = __builtin_shufflevector(a0, a1, 0, 1, 2, 3);
            f16x4 hf = __builtin_shufflevector(a2, a3, 0, 1, 2, 3);
            f16x8 a  = __builtin_shufflevector(lo, hf, 0, 1, 2, 3, 4, 5, 6, 7);
            accB = __builtin_amdgcn_mfma_f32_32x32x16_f16(a, bfrag, accB, 0, 0, 0);
        }
    }

    // ---- store: one base per tile, 16 constant-offset nt stores each ----
    float* ob0 = out + (wrow + 4 * hi) * 32 + rl;
    float* ob1 = ob0 + 32 * 32;
    #pragma unroll
    for (int e = 0; e < 16; ++e) {
        __builtin_nontemporal_store(accA[e], ob0 + (e & 3) * 32 + (e >> 2) * 256);
        __builtin_nontemporal_store(accB[e], ob1 + (e & 3) * 32 + (e >> 2) * 256);
    }
}

extern "C" void kernel_launch(void* const* d_in, const int* in_sizes, int n_in,
                              void* d_out, int out_size, void* d_ws, size_t ws_size,
                              hipStream_t stream) {
    const float* x = (const float*)d_in[0];
    const float* W = (const float*)d_in[1];
    float* out = (float*)d_out;
    unsigned short* bt = (unsigned short*)d_ws;    // 33 KiB table

    prep_btab_sym<<<32, 256, 0, stream>>>(W, bt);
    int nrows = in_sizes[0] / 32;          // 262144
    int grid  = nrows / 512;               // 512 blocks x 512 thr (2 tiles/wave)
    quadform_kernel<<<grid, 512, 0, stream>>>(x, bt, out);
}